// Round 7
// baseline (947.087 us; speedup 1.0000x reference)
//
#include <hip/hip_runtime.h>
#include <cstdint>
#include <cstddef>

typedef __attribute__((ext_vector_type(4))) float f32x4;
typedef __attribute__((ext_vector_type(8))) _Float16 h16x8;
typedef __attribute__((ext_vector_type(4))) _Float16 h16x4;
typedef __attribute__((ext_vector_type(8))) short s16x8;
typedef __attribute__((ext_vector_type(4))) short s16x4;
typedef unsigned short u16;
typedef unsigned long long u64;

// ---------- helpers ----------
static __device__ inline u16 f2h(float f) {
    _Float16 h = (_Float16)f;            // v_cvt_f16_f32 (RNE)
    return __builtin_bit_cast(u16, h);
}

static __device__ inline f32x4 mfma16(h16x8 a, h16x8 b, f32x4 c) {
    return __builtin_amdgcn_mfma_f32_16x16x32_f16(a, b, c, 0, 0, 0);
}

static __device__ inline float redsum16(float v) {
    v += __shfl_xor(v, 1);
    v += __shfl_xor(v, 2);
    v += __shfl_xor(v, 4);
    v += __shfl_xor(v, 8);
    return v;
}

// ---------- weight fp32 -> fp16 pack with scale ----------
__global__ __launch_bounds__(256) void cvt_h_kernel(const float* __restrict__ src,
                                                    u16* __restrict__ dst, float scale) {
    int i = (blockIdx.x * 256 + threadIdx.x) * 4;
    f32x4 v = *(const f32x4*)(src + i);
    s16x4 o;
    o[0] = (short)f2h(v[0] * scale); o[1] = (short)f2h(v[1] * scale);
    o[2] = (short)f2h(v[2] * scale); o[3] = (short)f2h(v[3] * scale);
    *(s16x4*)(dst + i) = o;
}

// ---------- geo mask bitmask ----------
__global__ __launch_bounds__(256) void mask_kernel(const float* __restrict__ xt,
                                                   const float* __restrict__ xh,
                                                   u64* __restrict__ mb) {
    int tid  = threadIdx.x;
    int lane = tid & 63;
    int wv   = blockIdx.x * 4 + (tid >> 6);
    int n    = wv >> 6;
    int mbk  = wv & 63;
    int m    = (mbk << 6) + lane;
    size_t hidx = ((size_t)n * 4096 + m) * 2;
    float dx = xt[2 * m]     - xh[hidx];
    float dy = xt[2 * m + 1] - xh[hidx + 1];
    bool p = sqrtf(dx * dx + dy * dy) < 0.2f;
    u64 bal = __ballot(p);
    if (lane == 0) mb[wv] = bal;
}

// ---------- projection GEMM, 128x128 tile, BK=64 (fp16 MFMA) ----------
// Y[m][n] = sum_k X[m][k]*W[n][k] + b[n]*bscale
// INF32: 1 = X fp32 (convert during staging), 0 = X fp16
// MODE : 1 = fp16 V-transposed (bh,64,HW), 2 = fp32 row-major, 3 = fp16 head-sep (bh,L,64)
template <int INF32, int MODE, int LSHIFT>
__global__ __launch_bounds__(256) void proj_kernel(const void* __restrict__ Xv,
                                                   const u16* __restrict__ Wb,
                                                   const float* __restrict__ bias,
                                                   float bscale,
                                                   void* __restrict__ Yv) {
    __shared__ u16 aT[128 * 72];   // stride 72 (36 words): 2-way bank = free
    __shared__ u16 bT[128 * 72];

    int tid  = threadIdx.x;
    int lane = tid & 63, w = tid >> 6, q = lane >> 4, m15 = lane & 15;
    int wm = w >> 1, wn = w & 1;
    int m0 = blockIdx.x * 128, n0 = blockIdx.y * 128;
    int sRow = tid >> 1, sC = (tid & 1) * 32;

    f32x4 acc[4][4];
#pragma unroll
    for (int i = 0; i < 4; ++i)
#pragma unroll
        for (int j = 0; j < 4; ++j) { f32x4 z = {0.f, 0.f, 0.f, 0.f}; acc[i][j] = z; }

    for (int kb = 0; kb < 512; kb += 64) {
        // stage A (128 rows x 64 k)
        if (INF32) {
            const float* X = (const float*)Xv;
#pragma unroll
            for (int j = 0; j < 8; ++j) {
                int col = sC + j * 4;
                f32x4 v = *(const f32x4*)(X + (size_t)(m0 + sRow) * 512 + kb + col);
                s16x4 o;
                o[0] = (short)f2h(v[0]); o[1] = (short)f2h(v[1]);
                o[2] = (short)f2h(v[2]); o[3] = (short)f2h(v[3]);
                *(s16x4*)(aT + sRow * 72 + col) = o;
            }
        } else {
            const u16* X = (const u16*)Xv;
#pragma unroll
            for (int j = 0; j < 4; ++j) {
                int col = sC + j * 8;
                s16x8 v = *(const s16x8*)(X + (size_t)(m0 + sRow) * 512 + kb + col);
                *(s16x8*)(aT + sRow * 72 + col) = v;
            }
        }
        // stage B (128 n-rows x 64 k)
#pragma unroll
        for (int j = 0; j < 4; ++j) {
            int col = sC + j * 8;
            s16x8 v = *(const s16x8*)(Wb + (size_t)(n0 + sRow) * 512 + kb + col);
            *(s16x8*)(bT + sRow * 72 + col) = v;
        }
        __syncthreads();
#pragma unroll
        for (int kk = 0; kk < 2; ++kk) {
            h16x8 af[4], bf[4];
#pragma unroll
            for (int t = 0; t < 4; ++t) {
                af[t] = *(const h16x8*)(aT + (wm * 64 + t * 16 + m15) * 72 + kk * 32 + q * 8);
                bf[t] = *(const h16x8*)(bT + (wn * 64 + t * 16 + m15) * 72 + kk * 32 + q * 8);
            }
#pragma unroll
            for (int am = 0; am < 4; ++am)
#pragma unroll
                for (int bn = 0; bn < 4; ++bn)
                    acc[am][bn] = mfma16(af[am], bf[bn], acc[am][bn]);
        }
        __syncthreads();
    }

    // epilogue: C/D layout col=lane&15, row=q*4+reg
#pragma unroll
    for (int am = 0; am < 4; ++am) {
        int mg = m0 + wm * 64 + am * 16 + q * 4;
#pragma unroll
        for (int bn = 0; bn < 4; ++bn) {
            int col = n0 + wn * 64 + bn * 16 + m15;
            float bv = bias[col] * bscale;
            if (MODE == 2) {
                float* Y = (float*)Yv;
#pragma unroll
                for (int r = 0; r < 4; ++r)
                    Y[(size_t)(mg + r) * 512 + col] = acc[am][bn][r] + bv;
            } else if (MODE == 3) {
                u16* Y = (u16*)Yv;
                int hh = col >> 6, d = col & 63;
#pragma unroll
                for (int r = 0; r < 4; ++r) {
                    int m = mg + r;
                    int bb = m >> LSHIFT;
                    int nn = m & ((1 << LSHIFT) - 1);
                    Y[(((size_t)(bb * 8 + hh) << LSHIFT) + nn) * 64 + d] = f2h(acc[am][bn][r] + bv);
                }
            } else {
                u16* Yt = (u16*)Yv;
                int bidx = mg >> 12, hw0 = mg & 4095;
                int hh = col >> 6, d = col & 63;
                s16x4 o;
#pragma unroll
                for (int r = 0; r < 4; ++r) o[r] = (short)f2h(acc[am][bn][r] + bv);
                *(s16x4*)(Yt + ((size_t)((bidx << 3) + hh) * 64 + d) * 4096 + hw0) = o;
            }
        }
    }
}

// ---------- fused attention: 16 q-rows x 4096 cols per block, 8 waves ----------
// SINGLE-PASS via LDS P-stash: phase 1 computes QK^T ONCE, masked exp -> full
// 16x4096 fp16 P strip in LDS (128 KB) + l partials. Phase 2: PV MFMA reading
// A-fragments straight from LDS P (unnormalized; ctx scaled by 1/l at end),
// interleaved with FULL-LINE normalized attn stores (LDS read-back, f32x4 ->
// 4 rows x 256B contiguous per store). Same K L2 traffic as the 2-pass 32-row
// version (2048 blocks x 512KB == 1024 x 2 x 512KB); half the MFMA/exp/VALU.
__global__ __launch_bounds__(512) void attn_kernel(const u16* __restrict__ Qh,
                                                   const u16* __restrict__ Kh,
                                                   const u16* __restrict__ Vt,
                                                   const u64* __restrict__ mbits,
                                                   float* __restrict__ attnO,
                                                   u16* __restrict__ ctxO) {
    __shared__ u16   P[16][4104];       // 131,328 B; stride 4104 u16 (16B-aligned rows)
    __shared__ u64   smask[1024];       // 16 rows x 64 words = 8 KB
    __shared__ float sred[8][16];
    __shared__ float srowi[16];
    __shared__ float sctx[1024];        // 16 rows x 64 d = 4 KB
    // total ~144.2 KB < 160 KB -> 1 block/CU

    int tid  = threadIdx.x;
    int lane = tid & 63, w = tid >> 6, q = lane >> 4, m15 = lane & 15;
    int i = blockIdx.x;
    int jj = i >> 3;
    int bh = (i & 7) * 4 + (jj & 3);    // XCD swizzle: 4 bh per XCD -> K+V fit its L2
    int n0 = (jj >> 2) * 16;            // 64 row-groups of 16
    int b = bh >> 3, h = bh & 7;

    for (int t = tid; t < 1024; t += 512) {
        smask[t] = mbits[(size_t)n0 * 64 + t];
        sctx[t]  = 0.f;
    }
    __syncthreads();

    // Q A-fragment (Q pre-scaled by 1/8)
    h16x8 aQ[2];
    {
        const u16* Qp = Qh + (((size_t)bh << 10) + n0 + m15) * 64 + q * 8;
        aQ[0] = *(const h16x8*)(Qp);
        aQ[1] = *(const h16x8*)(Qp + 32);
    }

    const u16* Kp = Kh + (((size_t)bh << 12) + (w << 9) + m15) * 64 + q * 8;
    const float L2E = 1.44269504f;

    // ---- Phase 1: QK^T once -> masked exp -> P (LDS) + l partials ----
    float ls[4] = {0.f, 0.f, 0.f, 0.f};
    for (int cc = 0; cc < 8; ++cc) {
        int widx = w * 8 + cc;
        u64 mk[4];
#pragma unroll
        for (int r = 0; r < 4; ++r) mk[r] = smask[(q * 4 + r) * 64 + widx];
#pragma unroll
        for (int tt = 0; tt < 4; ++tt) {
            const u16* kp = Kp + (size_t)(cc * 4 + tt) * (16 * 64);
            h16x8 b0 = *(const h16x8*)(kp);
            h16x8 b1 = *(const h16x8*)(kp + 32);
            f32x4 z = {0.f, 0.f, 0.f, 0.f};
            f32x4 c0 = mfma16(aQ[0], b0, mfma16(aQ[1], b1, z));
            int col = (w << 9) + cc * 64 + tt * 16 + m15;
            int bit = tt * 16 + m15;
#pragma unroll
            for (int r = 0; r < 4; ++r) {
                float p = ((mk[r] >> bit) & 1ull) ? exp2f(c0[r] * L2E) : 0.f;
                ls[r] += p;
                P[q * 4 + r][col] = f2h(p);
            }
        }
    }
#pragma unroll
    for (int r = 0; r < 4; ++r) {
        float v = redsum16(ls[r]);
        if (m15 == 0) sred[w][q * 4 + r] = v;
    }
    __syncthreads();
    if (tid < 16) {
        float ss = 0.f;
#pragma unroll
        for (int ww = 0; ww < 8; ++ww) ss += sred[ww][tid];
        srowi[tid] = 1.0f / ss;
    }
    __syncthreads();
    float iv[4];   // ctx-scale: row = q*4 + r
    float ivr[4];  // store-scale: row = s*4 + q
#pragma unroll
    for (int r = 0; r < 4; ++r) {
        iv[r]  = srowi[q * 4 + r];
        ivr[r] = srowi[r * 4 + q];
    }

    // ---- Phase 2: PV (A-fragment from LDS P) + full-line normalized stores ----
    const u16* Vp = Vt + (((size_t)bh << 6) + m15) * 4096 + (w << 9) + q * 8;
    int c0l = m15 * 4;   // 4-float column group for the store read-back

    f32x4 ctxa[4];
#pragma unroll
    for (int dt = 0; dt < 4; ++dt) { f32x4 z = {0.f, 0.f, 0.f, 0.f}; ctxa[dt] = z; }

    for (int cc = 0; cc < 8; ++cc) {
        // PV MFMA (unnormalized P)
#pragma unroll
        for (int half = 0; half < 2; ++half) {
            h16x8 aP = *(const h16x8*)(&P[m15][(w << 9) + cc * 64 + half * 32 + q * 8]);
#pragma unroll
            for (int dt = 0; dt < 4; ++dt) {
                h16x8 bV = *(const h16x8*)(Vp + (size_t)dt * (16 * 4096) + cc * 64 + half * 32);
                ctxa[dt] = mfma16(aP, bV, ctxa[dt]);
            }
        }
        // full-line attn stores: lane reads 4 contiguous fp16 of row s*4+q,
        // wave covers 4 rows x 256B contiguous per store instruction
        float* bp = attnO + (((size_t)bh << 10) + n0) * 4096 + (w << 9) + cc * 64 + c0l;
#pragma unroll
        for (int s = 0; s < 4; ++s) {
            int row = s * 4 + q;
            h16x4 hv = *(const h16x4*)(&P[row][(w << 9) + cc * 64 + c0l]);
            f32x4 o;
            o[0] = (float)hv[0] * ivr[s];
            o[1] = (float)hv[1] * ivr[s];
            o[2] = (float)hv[2] * ivr[s];
            o[3] = (float)hv[3] * ivr[s];
            __builtin_nontemporal_store(o, (f32x4*)(bp + (size_t)row * 4096));
        }
    }

    // ---- ctx reduce + store ----
#pragma unroll
    for (int dt = 0; dt < 4; ++dt)
#pragma unroll
        for (int r = 0; r < 4; ++r)
            atomicAdd(&sctx[(q * 4 + r) * 64 + dt * 16 + m15], ctxa[dt][r] * iv[r]);
    __syncthreads();
    for (int t = tid; t < 1024; t += 512) {
        int rr = t >> 6, d = t & 63;
        ctxO[(((size_t)b << 10) + n0 + rr) * 512 + h * 64 + d] = f2h(sctx[t]);
    }
}

// ---------- launch ----------
extern "C" void kernel_launch(void* const* d_in, const int* in_sizes, int n_in,
                              void* d_out, int out_size, void* d_ws, size_t ws_size,
                              hipStream_t stream) {
    (void)in_sizes; (void)n_in; (void)out_size; (void)ws_size;
    const float* query = (const float*)d_in[0];
    const float* key   = (const float*)d_in[1];
    const float* value = (const float*)d_in[2];
    const float* x_tilde = (const float*)d_in[3];
    const float* x_hat   = (const float*)d_in[4];
    const float* Wq = (const float*)d_in[5];  const float* bq = (const float*)d_in[6];
    const float* Wk = (const float*)d_in[7];  const float* bk = (const float*)d_in[8];
    const float* Wv = (const float*)d_in[9];  const float* bv = (const float*)d_in[10];
    const float* Wo = (const float*)d_in[11]; const float* bo = (const float*)d_in[12];

    char* ws = (char*)d_ws;
    u16* wq   = (u16*)(ws + 0);
    u16* wk   = (u16*)(ws + 524288);
    u16* wv   = (u16*)(ws + 1048576);
    u16* wo   = (u16*)(ws + 1572864);
    u16* Qh   = (u16*)(ws + 2097152);    // (bh, 1024, 64) fp16, pre-scaled 1/8
    u16* Kh   = (u16*)(ws + 6291456);    // (bh, 4096, 64) fp16
    u16* Vtb  = (u16*)(ws + 23068672);   // (bh, 64, 4096) fp16
    u16* ctxb = (u16*)(ws + 39845888);   // (B*N, 512) fp16
    u64* mbits = (u64*)(ws + 44040192);  // (1024, 64) u64

    cvt_h_kernel<<<256, 256, 0, stream>>>(Wq, wq, 0.125f);  // fold 1/sqrt(dk) into Q
    cvt_h_kernel<<<256, 256, 0, stream>>>(Wk, wk, 1.0f);
    cvt_h_kernel<<<256, 256, 0, stream>>>(Wv, wv, 1.0f);
    cvt_h_kernel<<<256, 256, 0, stream>>>(Wo, wo, 1.0f);
    mask_kernel<<<16384, 256, 0, stream>>>(x_tilde, x_hat, mbits);

    proj_kernel<1, 3, 10><<<dim3(32, 4),  256, 0, stream>>>(query, wq, bq, 0.125f, Qh);
    proj_kernel<1, 3, 12><<<dim3(128, 4), 256, 0, stream>>>(key,   wk, bk, 1.0f,   Kh);
    proj_kernel<1, 1, 12><<<dim3(128, 4), 256, 0, stream>>>(value, wv, bv, 1.0f,   Vtb);

    float* attnO = (float*)d_out + 2097152;
    attn_kernel<<<2048, 512, 0, stream>>>(Qh, Kh, Vtb, mbits, attnO, ctxb);

    proj_kernel<0, 2, 10><<<dim3(32, 4), 256, 0, stream>>>(ctxb, wo, bo, 1.0f, d_out);
}

// Round 8
// 889.587 us; speedup vs baseline: 1.0646x; 1.0646x over previous
//
#include <hip/hip_runtime.h>
#include <cstdint>
#include <cstddef>

typedef __attribute__((ext_vector_type(4))) float f32x4;
typedef __attribute__((ext_vector_type(8))) _Float16 h16x8;
typedef __attribute__((ext_vector_type(4))) _Float16 h16x4;
typedef __attribute__((ext_vector_type(8))) short s16x8;
typedef __attribute__((ext_vector_type(4))) short s16x4;
typedef unsigned short u16;
typedef unsigned long long u64;

// ---------- helpers ----------
static __device__ inline u16 f2h(float f) {
    _Float16 h = (_Float16)f;            // v_cvt_f16_f32 (RNE)
    return __builtin_bit_cast(u16, h);
}

static __device__ inline f32x4 mfma16(h16x8 a, h16x8 b, f32x4 c) {
    return __builtin_amdgcn_mfma_f32_16x16x32_f16(a, b, c, 0, 0, 0);
}

static __device__ inline float redsum16(float v) {
    v += __shfl_xor(v, 1);
    v += __shfl_xor(v, 2);
    v += __shfl_xor(v, 4);
    v += __shfl_xor(v, 8);
    return v;
}

// ---------- weight fp32 -> fp16 pack with scale ----------
__global__ __launch_bounds__(256) void cvt_h_kernel(const float* __restrict__ src,
                                                    u16* __restrict__ dst, float scale) {
    int i = (blockIdx.x * 256 + threadIdx.x) * 4;
    f32x4 v = *(const f32x4*)(src + i);
    s16x4 o;
    o[0] = (short)f2h(v[0] * scale); o[1] = (short)f2h(v[1] * scale);
    o[2] = (short)f2h(v[2] * scale); o[3] = (short)f2h(v[3] * scale);
    *(s16x4*)(dst + i) = o;
}

// ---------- geo mask bitmask ----------
__global__ __launch_bounds__(256) void mask_kernel(const float* __restrict__ xt,
                                                   const float* __restrict__ xh,
                                                   u64* __restrict__ mb) {
    int tid  = threadIdx.x;
    int lane = tid & 63;
    int wv   = blockIdx.x * 4 + (tid >> 6);
    int n    = wv >> 6;
    int mbk  = wv & 63;
    int m    = (mbk << 6) + lane;
    size_t hidx = ((size_t)n * 4096 + m) * 2;
    float dx = xt[2 * m]     - xh[hidx];
    float dy = xt[2 * m + 1] - xh[hidx + 1];
    bool p = sqrtf(dx * dx + dy * dy) < 0.2f;
    u64 bal = __ballot(p);
    if (lane == 0) mb[wv] = bal;
}

// ---------- projection GEMM, 128x128 tile, BK=64 (fp16 MFMA) ----------
// Y[m][n] = sum_k X[m][k]*W[n][k] + b[n]*bscale
// INF32: 1 = X fp32 (convert during staging), 0 = X fp16
// MODE : 1 = fp16 V-transposed (bh,64,HW), 2 = fp32 row-major, 3 = fp16 head-sep (bh,L,64)
template <int INF32, int MODE, int LSHIFT>
__global__ __launch_bounds__(256) void proj_kernel(const void* __restrict__ Xv,
                                                   const u16* __restrict__ Wb,
                                                   const float* __restrict__ bias,
                                                   float bscale,
                                                   void* __restrict__ Yv) {
    __shared__ u16 aT[128 * 72];   // stride 72 (36 words): 2-way bank = free
    __shared__ u16 bT[128 * 72];

    int tid  = threadIdx.x;
    int lane = tid & 63, w = tid >> 6, q = lane >> 4, m15 = lane & 15;
    int wm = w >> 1, wn = w & 1;
    int m0 = blockIdx.x * 128, n0 = blockIdx.y * 128;
    int sRow = tid >> 1, sC = (tid & 1) * 32;

    f32x4 acc[4][4];
#pragma unroll
    for (int i = 0; i < 4; ++i)
#pragma unroll
        for (int j = 0; j < 4; ++j) { f32x4 z = {0.f, 0.f, 0.f, 0.f}; acc[i][j] = z; }

    for (int kb = 0; kb < 512; kb += 64) {
        // stage A (128 rows x 64 k)
        if (INF32) {
            const float* X = (const float*)Xv;
#pragma unroll
            for (int j = 0; j < 8; ++j) {
                int col = sC + j * 4;
                f32x4 v = *(const f32x4*)(X + (size_t)(m0 + sRow) * 512 + kb + col);
                s16x4 o;
                o[0] = (short)f2h(v[0]); o[1] = (short)f2h(v[1]);
                o[2] = (short)f2h(v[2]); o[3] = (short)f2h(v[3]);
                *(s16x4*)(aT + sRow * 72 + col) = o;
            }
        } else {
            const u16* X = (const u16*)Xv;
#pragma unroll
            for (int j = 0; j < 4; ++j) {
                int col = sC + j * 8;
                s16x8 v = *(const s16x8*)(X + (size_t)(m0 + sRow) * 512 + kb + col);
                *(s16x8*)(aT + sRow * 72 + col) = v;
            }
        }
        // stage B (128 n-rows x 64 k)
#pragma unroll
        for (int j = 0; j < 4; ++j) {
            int col = sC + j * 8;
            s16x8 v = *(const s16x8*)(Wb + (size_t)(n0 + sRow) * 512 + kb + col);
            *(s16x8*)(bT + sRow * 72 + col) = v;
        }
        __syncthreads();
#pragma unroll
        for (int kk = 0; kk < 2; ++kk) {
            h16x8 af[4], bf[4];
#pragma unroll
            for (int t = 0; t < 4; ++t) {
                af[t] = *(const h16x8*)(aT + (wm * 64 + t * 16 + m15) * 72 + kk * 32 + q * 8);
                bf[t] = *(const h16x8*)(bT + (wn * 64 + t * 16 + m15) * 72 + kk * 32 + q * 8);
            }
#pragma unroll
            for (int am = 0; am < 4; ++am)
#pragma unroll
                for (int bn = 0; bn < 4; ++bn)
                    acc[am][bn] = mfma16(af[am], bf[bn], acc[am][bn]);
        }
        __syncthreads();
    }

    // epilogue: C/D layout col=lane&15, row=q*4+reg
#pragma unroll
    for (int am = 0; am < 4; ++am) {
        int mg = m0 + wm * 64 + am * 16 + q * 4;
#pragma unroll
        for (int bn = 0; bn < 4; ++bn) {
            int col = n0 + wn * 64 + bn * 16 + m15;
            float bv = bias[col] * bscale;
            if (MODE == 2) {
                float* Y = (float*)Yv;
#pragma unroll
                for (int r = 0; r < 4; ++r)
                    Y[(size_t)(mg + r) * 512 + col] = acc[am][bn][r] + bv;
            } else if (MODE == 3) {
                u16* Y = (u16*)Yv;
                int hh = col >> 6, d = col & 63;
#pragma unroll
                for (int r = 0; r < 4; ++r) {
                    int m = mg + r;
                    int bb = m >> LSHIFT;
                    int nn = m & ((1 << LSHIFT) - 1);
                    Y[(((size_t)(bb * 8 + hh) << LSHIFT) + nn) * 64 + d] = f2h(acc[am][bn][r] + bv);
                }
            } else {
                u16* Yt = (u16*)Yv;
                int bidx = mg >> 12, hw0 = mg & 4095;
                int hh = col >> 6, d = col & 63;
                s16x4 o;
#pragma unroll
                for (int r = 0; r < 4; ++r) o[r] = (short)f2h(acc[am][bn][r] + bv);
                *(s16x4*)(Yt + ((size_t)((bidx << 3) + hh) * 64 + d) * 4096 + hw0) = o;
            }
        }
    }
}

// ---------- fused attention: 32 q-rows x 4096 cols per block, 8 waves ----------
// r5 two-pass structure with LDS cut 62KB -> 44KB so 3 blocks/CU fit (24 waves,
// +50% latency hiding). sps halved: one 16-row strip; the two row-groups are
// processed SEQUENTIALLY in pass 2 (g=1 p-values parked in 16 VGPRs while g=0
// uses the strip; V fragments cached in regs so K/V traffic is unchanged).
__global__ __launch_bounds__(512) void attn_kernel(const u16* __restrict__ Qh,
                                                   const u16* __restrict__ Kh,
                                                   const u16* __restrict__ Vt,
                                                   const u64* __restrict__ mbits,
                                                   float* __restrict__ attnO,
                                                   u16* __restrict__ ctxO) {
    __shared__ u64   smask[2048];        // 32 rows x 64 words = 16 KB
    __shared__ float sred[8][32];
    __shared__ float srowi[32];
    __shared__ u16   sps[8][16 * 72];    // per-wave P strip (one row-group) = 18.4 KB
    __shared__ float sctx[2048];         // 8 KB
    // total ~44.2 KB -> 3 blocks/CU

    int tid  = threadIdx.x;
    int lane = tid & 63, w = tid >> 6, q = lane >> 4, m15 = lane & 15;
    int i = blockIdx.x;
    int jj = i >> 3;
    int bh = (i & 7) * 4 + (jj & 3);     // XCD swizzle: 4 bh per XCD -> K+V fit its L2
    int n0 = (jj >> 2) * 32;
    int b = bh >> 3, h = bh & 7;

    for (int t = tid; t < 2048; t += 512) {
        smask[t] = mbits[(size_t)n0 * 64 + t];
        sctx[t]  = 0.f;
    }
    __syncthreads();

    // Q A-fragments for both 16-row groups (Q pre-scaled by 1/8)
    h16x8 aQ[2][2];
#pragma unroll
    for (int g = 0; g < 2; ++g) {
        const u16* Qp = Qh + (((size_t)bh << 10) + n0 + g * 16 + m15) * 64 + q * 8;
        aQ[g][0] = *(const h16x8*)(Qp);
        aQ[g][1] = *(const h16x8*)(Qp + 32);
    }

    const u16* Kp = Kh + (((size_t)bh << 12) + (w << 9) + m15) * 64 + q * 8;
    const float L2E = 1.44269504f;

    // ---- Pass 1: l = sum exp(score) ----
    float ls[2][4] = {{0.f,0.f,0.f,0.f},{0.f,0.f,0.f,0.f}};
    for (int t4 = 0; t4 < 8; ++t4) {
        int widx = w * 8 + t4;
        u64 mk[2][4];
#pragma unroll
        for (int g = 0; g < 2; ++g)
#pragma unroll
            for (int r = 0; r < 4; ++r) mk[g][r] = smask[(g * 16 + q * 4 + r) * 64 + widx];
#pragma unroll
        for (int tt = 0; tt < 4; ++tt) {
            const u16* kp = Kp + (size_t)(t4 * 4 + tt) * (16 * 64);
            h16x8 b0 = *(const h16x8*)(kp);
            h16x8 b1 = *(const h16x8*)(kp + 32);
            f32x4 z = {0.f, 0.f, 0.f, 0.f};
            f32x4 c0 = mfma16(aQ[0][0], b0, mfma16(aQ[0][1], b1, z));
            f32x4 c1 = mfma16(aQ[1][0], b0, mfma16(aQ[1][1], b1, z));
            int bit = tt * 16 + m15;
#pragma unroll
            for (int r = 0; r < 4; ++r) {
                float p0 = ((mk[0][r] >> bit) & 1ull) ? exp2f(c0[r] * L2E) : 0.f;
                float p1 = ((mk[1][r] >> bit) & 1ull) ? exp2f(c1[r] * L2E) : 0.f;
                ls[0][r] += p0;
                ls[1][r] += p1;
            }
        }
    }
#pragma unroll
    for (int g = 0; g < 2; ++g)
#pragma unroll
        for (int r = 0; r < 4; ++r) {
            float v = redsum16(ls[g][r]);
            if (m15 == 0) sred[w][g * 16 + q * 4 + r] = v;
        }
    __syncthreads();
    if (tid < 32) {
        float ss = 0.f;
#pragma unroll
        for (int ww = 0; ww < 8; ++ww) ss += sred[ww][tid];
        srowi[tid] = 1.0f / ss;
    }
    __syncthreads();
    float iv[2][4];   // ctx-scale: row = q*4 + r
    float ivr[2][4];  // store-scale: row = s*4 + q
#pragma unroll
    for (int g = 0; g < 2; ++g)
#pragma unroll
        for (int r = 0; r < 4; ++r) {
            iv[g][r]  = srowi[g * 16 + q * 4 + r];
            ivr[g][r] = srowi[g * 16 + r * 4 + q];
        }

    // ---- Pass 2: recompute, per-group: P strip -> PV -> full-line stores ----
    const u16* Vp = Vt + (((size_t)bh << 6) + m15) * 4096 + (w << 9) + q * 8;
    int c0l = m15 * 4;   // 4-float column group for the store read-back

    f32x4 ctxa[2][4];
#pragma unroll
    for (int g = 0; g < 2; ++g)
#pragma unroll
        for (int dt = 0; dt < 4; ++dt) { f32x4 z = {0.f, 0.f, 0.f, 0.f}; ctxa[g][dt] = z; }

    for (int cc = 0; cc < 8; ++cc) {
        int widx = w * 8 + cc;
        u64 mk[2][4];
#pragma unroll
        for (int g = 0; g < 2; ++g)
#pragma unroll
            for (int r = 0; r < 4; ++r) mk[g][r] = smask[(g * 16 + q * 4 + r) * 64 + widx];

        float p1v[4][4];   // g=1 p-values parked in regs while strip holds g=0
#pragma unroll
        for (int tt = 0; tt < 4; ++tt) {
            const u16* kp = Kp + (size_t)(cc * 4 + tt) * (16 * 64);
            h16x8 b0 = *(const h16x8*)(kp);
            h16x8 b1 = *(const h16x8*)(kp + 32);
            f32x4 z = {0.f, 0.f, 0.f, 0.f};
            f32x4 c0 = mfma16(aQ[0][0], b0, mfma16(aQ[0][1], b1, z));
            f32x4 c1 = mfma16(aQ[1][0], b0, mfma16(aQ[1][1], b1, z));
            int bit = tt * 16 + m15;
#pragma unroll
            for (int r = 0; r < 4; ++r) {
                float p0 = ((mk[0][r] >> bit) & 1ull) ? exp2f(c0[r] * L2E) : 0.f;
                p1v[tt][r] = ((mk[1][r] >> bit) & 1ull) ? exp2f(c1[r] * L2E) : 0.f;
                sps[w][(q * 4 + r) * 72 + tt * 16 + m15] = f2h(p0);
            }
        }
        // V fragments cached once, reused by both groups
        h16x8 bV[2][4];
#pragma unroll
        for (int half = 0; half < 2; ++half)
#pragma unroll
            for (int dt = 0; dt < 4; ++dt)
                bV[half][dt] = *(const h16x8*)(Vp + (size_t)dt * (16 * 4096) + cc * 64 + half * 32);

#pragma unroll
        for (int g = 0; g < 2; ++g) {
            if (g == 1) {
                // swap strip to g=1 from parked regs
#pragma unroll
                for (int tt = 0; tt < 4; ++tt)
#pragma unroll
                    for (int r = 0; r < 4; ++r)
                        sps[w][(q * 4 + r) * 72 + tt * 16 + m15] = f2h(p1v[tt][r]);
            }
            // PV MFMA (unnormalized P; ctx scaled by 1/l at the end)
#pragma unroll
            for (int half = 0; half < 2; ++half) {
                h16x8 aP = *(const h16x8*)(&sps[w][m15 * 72 + half * 32 + q * 8]);
#pragma unroll
                for (int dt = 0; dt < 4; ++dt)
                    ctxa[g][dt] = mfma16(aP, bV[half][dt], ctxa[g][dt]);
            }
            // full-line attn stores: lane reads 4 contiguous fp16 of row s*4+q,
            // wave covers 4 rows x 256B contiguous per store instruction
            float* bp = attnO + (((size_t)bh << 10) + n0 + g * 16) * 4096 + (w << 9) + cc * 64 + c0l;
#pragma unroll
            for (int s = 0; s < 4; ++s) {
                int row = s * 4 + q;
                h16x4 hv = *(const h16x4*)(&sps[w][row * 72 + c0l]);
                f32x4 o;
                o[0] = (float)hv[0] * ivr[g][s];
                o[1] = (float)hv[1] * ivr[g][s];
                o[2] = (float)hv[2] * ivr[g][s];
                o[3] = (float)hv[3] * ivr[g][s];
                __builtin_nontemporal_store(o, (f32x4*)(bp + (size_t)row * 4096));
            }
        }
    }

    // ---- ctx reduce + store ----
#pragma unroll
    for (int g = 0; g < 2; ++g)
#pragma unroll
        for (int dt = 0; dt < 4; ++dt)
#pragma unroll
            for (int r = 0; r < 4; ++r)
                atomicAdd(&sctx[(g * 16 + q * 4 + r) * 64 + dt * 16 + m15],
                          ctxa[g][dt][r] * iv[g][r]);
    __syncthreads();
    for (int t = tid; t < 2048; t += 512) {
        int rr = t >> 6, d = t & 63;
        ctxO[(((size_t)b << 10) + n0 + rr) * 512 + h * 64 + d] = f2h(sctx[t]);
    }
}

// ---------- launch ----------
extern "C" void kernel_launch(void* const* d_in, const int* in_sizes, int n_in,
                              void* d_out, int out_size, void* d_ws, size_t ws_size,
                              hipStream_t stream) {
    (void)in_sizes; (void)n_in; (void)out_size; (void)ws_size;
    const float* query = (const float*)d_in[0];
    const float* key   = (const float*)d_in[1];
    const float* value = (const float*)d_in[2];
    const float* x_tilde = (const float*)d_in[3];
    const float* x_hat   = (const float*)d_in[4];
    const float* Wq = (const float*)d_in[5];  const float* bq = (const float*)d_in[6];
    const float* Wk = (const float*)d_in[7];  const float* bk = (const float*)d_in[8];
    const float* Wv = (const float*)d_in[9];  const float* bv = (const float*)d_in[10];
    const float* Wo = (const float*)d_in[11]; const float* bo = (const float*)d_in[12];

    char* ws = (char*)d_ws;
    u16* wq   = (u16*)(ws + 0);
    u16* wk   = (u16*)(ws + 524288);
    u16* wv   = (u16*)(ws + 1048576);
    u16* wo   = (u16*)(ws + 1572864);
    u16* Qh   = (u16*)(ws + 2097152);    // (bh, 1024, 64) fp16, pre-scaled 1/8
    u16* Kh   = (u16*)(ws + 6291456);    // (bh, 4096, 64) fp16
    u16* Vtb  = (u16*)(ws + 23068672);   // (bh, 64, 4096) fp16
    u16* ctxb = (u16*)(ws + 39845888);   // (B*N, 512) fp16
    u64* mbits = (u64*)(ws + 44040192);  // (1024, 64) u64

    cvt_h_kernel<<<256, 256, 0, stream>>>(Wq, wq, 0.125f);  // fold 1/sqrt(dk) into Q
    cvt_h_kernel<<<256, 256, 0, stream>>>(Wk, wk, 1.0f);
    cvt_h_kernel<<<256, 256, 0, stream>>>(Wv, wv, 1.0f);
    cvt_h_kernel<<<256, 256, 0, stream>>>(Wo, wo, 1.0f);
    mask_kernel<<<16384, 256, 0, stream>>>(x_tilde, x_hat, mbits);

    proj_kernel<1, 3, 10><<<dim3(32, 4),  256, 0, stream>>>(query, wq, bq, 0.125f, Qh);
    proj_kernel<1, 3, 12><<<dim3(128, 4), 256, 0, stream>>>(key,   wk, bk, 1.0f,   Kh);
    proj_kernel<1, 1, 12><<<dim3(128, 4), 256, 0, stream>>>(value, wv, bv, 1.0f,   Vtb);

    float* attnO = (float*)d_out + 2097152;
    attn_kernel<<<1024, 512, 0, stream>>>(Qh, Kh, Vtb, mbits, attnO, ctxb);

    proj_kernel<0, 2, 10><<<dim3(32, 4), 256, 0, stream>>>(ctxb, wo, bo, 1.0f, d_out);
}

// Round 9
// 887.463 us; speedup vs baseline: 1.0672x; 1.0024x over previous
//
#include <hip/hip_runtime.h>
#include <cstdint>
#include <cstddef>

typedef __attribute__((ext_vector_type(4))) float f32x4;
typedef __attribute__((ext_vector_type(8))) _Float16 h16x8;
typedef __attribute__((ext_vector_type(4))) _Float16 h16x4;
typedef __attribute__((ext_vector_type(8))) short s16x8;
typedef __attribute__((ext_vector_type(4))) short s16x4;
typedef unsigned short u16;
typedef unsigned long long u64;

// ---------- helpers ----------
static __device__ inline u16 f2h(float f) {
    _Float16 h = (_Float16)f;            // v_cvt_f16_f32 (RNE)
    return __builtin_bit_cast(u16, h);
}

static __device__ inline f32x4 mfma16(h16x8 a, h16x8 b, f32x4 c) {
    return __builtin_amdgcn_mfma_f32_16x16x32_f16(a, b, c, 0, 0, 0);
}

static __device__ inline float redsum16(float v) {
    v += __shfl_xor(v, 1);
    v += __shfl_xor(v, 2);
    v += __shfl_xor(v, 4);
    v += __shfl_xor(v, 8);
    return v;
}

// ---------- weight fp32 -> fp16 pack with scale ----------
__global__ __launch_bounds__(256) void cvt_h_kernel(const float* __restrict__ src,
                                                    u16* __restrict__ dst, float scale) {
    int i = (blockIdx.x * 256 + threadIdx.x) * 4;
    f32x4 v = *(const f32x4*)(src + i);
    s16x4 o;
    o[0] = (short)f2h(v[0] * scale); o[1] = (short)f2h(v[1] * scale);
    o[2] = (short)f2h(v[2] * scale); o[3] = (short)f2h(v[3] * scale);
    *(s16x4*)(dst + i) = o;
}

// ---------- geo mask bitmask ----------
__global__ __launch_bounds__(256) void mask_kernel(const float* __restrict__ xt,
                                                   const float* __restrict__ xh,
                                                   u64* __restrict__ mb) {
    int tid  = threadIdx.x;
    int lane = tid & 63;
    int wv   = blockIdx.x * 4 + (tid >> 6);
    int n    = wv >> 6;
    int mbk  = wv & 63;
    int m    = (mbk << 6) + lane;
    size_t hidx = ((size_t)n * 4096 + m) * 2;
    float dx = xt[2 * m]     - xh[hidx];
    float dy = xt[2 * m + 1] - xh[hidx + 1];
    bool p = sqrtf(dx * dx + dy * dy) < 0.2f;
    u64 bal = __ballot(p);
    if (lane == 0) mb[wv] = bal;
}

// ---------- projection GEMM, 128x128 tile, BK=64 (fp16 MFMA) ----------
// Y[m][n] = sum_k X[m][k]*W[n][k] + b[n]*bscale
// INF32: 1 = X fp32 (convert during staging), 0 = X fp16
// MODE : 1 = fp16 V-transposed (bh,64,HW), 2 = fp32 row-major, 3 = fp16 head-sep (bh,L,64)
template <int INF32, int MODE, int LSHIFT>
__global__ __launch_bounds__(256) void proj_kernel(const void* __restrict__ Xv,
                                                   const u16* __restrict__ Wb,
                                                   const float* __restrict__ bias,
                                                   float bscale,
                                                   void* __restrict__ Yv) {
    __shared__ u16 aT[128 * 72];   // stride 72 (36 words): 2-way bank = free
    __shared__ u16 bT[128 * 72];

    int tid  = threadIdx.x;
    int lane = tid & 63, w = tid >> 6, q = lane >> 4, m15 = lane & 15;
    int wm = w >> 1, wn = w & 1;
    int m0 = blockIdx.x * 128, n0 = blockIdx.y * 128;
    int sRow = tid >> 1, sC = (tid & 1) * 32;

    f32x4 acc[4][4];
#pragma unroll
    for (int i = 0; i < 4; ++i)
#pragma unroll
        for (int j = 0; j < 4; ++j) { f32x4 z = {0.f, 0.f, 0.f, 0.f}; acc[i][j] = z; }

    for (int kb = 0; kb < 512; kb += 64) {
        // stage A (128 rows x 64 k)
        if (INF32) {
            const float* X = (const float*)Xv;
#pragma unroll
            for (int j = 0; j < 8; ++j) {
                int col = sC + j * 4;
                f32x4 v = *(const f32x4*)(X + (size_t)(m0 + sRow) * 512 + kb + col);
                s16x4 o;
                o[0] = (short)f2h(v[0]); o[1] = (short)f2h(v[1]);
                o[2] = (short)f2h(v[2]); o[3] = (short)f2h(v[3]);
                *(s16x4*)(aT + sRow * 72 + col) = o;
            }
        } else {
            const u16* X = (const u16*)Xv;
#pragma unroll
            for (int j = 0; j < 4; ++j) {
                int col = sC + j * 8;
                s16x8 v = *(const s16x8*)(X + (size_t)(m0 + sRow) * 512 + kb + col);
                *(s16x8*)(aT + sRow * 72 + col) = v;
            }
        }
        // stage B (128 n-rows x 64 k)
#pragma unroll
        for (int j = 0; j < 4; ++j) {
            int col = sC + j * 8;
            s16x8 v = *(const s16x8*)(Wb + (size_t)(n0 + sRow) * 512 + kb + col);
            *(s16x8*)(bT + sRow * 72 + col) = v;
        }
        __syncthreads();
#pragma unroll
        for (int kk = 0; kk < 2; ++kk) {
            h16x8 af[4], bf[4];
#pragma unroll
            for (int t = 0; t < 4; ++t) {
                af[t] = *(const h16x8*)(aT + (wm * 64 + t * 16 + m15) * 72 + kk * 32 + q * 8);
                bf[t] = *(const h16x8*)(bT + (wn * 64 + t * 16 + m15) * 72 + kk * 32 + q * 8);
            }
#pragma unroll
            for (int am = 0; am < 4; ++am)
#pragma unroll
                for (int bn = 0; bn < 4; ++bn)
                    acc[am][bn] = mfma16(af[am], bf[bn], acc[am][bn]);
        }
        __syncthreads();
    }

    // epilogue: C/D layout col=lane&15, row=q*4+reg
#pragma unroll
    for (int am = 0; am < 4; ++am) {
        int mg = m0 + wm * 64 + am * 16 + q * 4;
#pragma unroll
        for (int bn = 0; bn < 4; ++bn) {
            int col = n0 + wn * 64 + bn * 16 + m15;
            float bv = bias[col] * bscale;
            if (MODE == 2) {
                float* Y = (float*)Yv;
#pragma unroll
                for (int r = 0; r < 4; ++r)
                    Y[(size_t)(mg + r) * 512 + col] = acc[am][bn][r] + bv;
            } else if (MODE == 3) {
                u16* Y = (u16*)Yv;
                int hh = col >> 6, d = col & 63;
#pragma unroll
                for (int r = 0; r < 4; ++r) {
                    int m = mg + r;
                    int bb = m >> LSHIFT;
                    int nn = m & ((1 << LSHIFT) - 1);
                    Y[(((size_t)(bb * 8 + hh) << LSHIFT) + nn) * 64 + d] = f2h(acc[am][bn][r] + bv);
                }
            } else {
                u16* Yt = (u16*)Yv;
                int bidx = mg >> 12, hw0 = mg & 4095;
                int hh = col >> 6, d = col & 63;
                s16x4 o;
#pragma unroll
                for (int r = 0; r < 4; ++r) o[r] = (short)f2h(acc[am][bn][r] + bv);
                *(s16x4*)(Yt + ((size_t)((bidx << 3) + hh) * 64 + d) * 4096 + hw0) = o;
            }
        }
    }
}

// ---------- fused attention: 32 q-rows x 4096 cols per block, 8 waves ----------
// r8 structure; ONE change: block->(bh,n0) mapping re-sequenced so each XCD
// works 2 bh at a time (2MB K+V, was 4MB = full L2) in two phases, with the
// 2 panels interleaved on consecutive blocks. Goal: K reads become L2 hits
// (~200cy) instead of L3/HBM (~900cy) -> latency-bound kernel speeds ~2x.
__global__ __launch_bounds__(512) void attn_kernel(const u16* __restrict__ Qh,
                                                   const u16* __restrict__ Kh,
                                                   const u16* __restrict__ Vt,
                                                   const u64* __restrict__ mbits,
                                                   float* __restrict__ attnO,
                                                   u16* __restrict__ ctxO) {
    __shared__ u64   smask[2048];        // 32 rows x 64 words = 16 KB
    __shared__ float sred[8][32];
    __shared__ float srowi[32];
    __shared__ u16   sps[8][16 * 72];    // per-wave P strip (one row-group) = 18.4 KB
    __shared__ float sctx[2048];         // 8 KB

    int tid  = threadIdx.x;
    int lane = tid & 63, w = tid >> 6, q = lane >> 4, m15 = lane & 15;
    int i = blockIdx.x;
    int xcd = i & 7, jj = i >> 3;
    // phase = jj>>6 (first 64 jj: bh pair {4x,4x+1}; last 64: {4x+2,4x+3});
    // jj&1 interleaves the pair; n0 advances every 2 blocks.
    int bh = xcd * 4 + ((jj >> 6) << 1) + (jj & 1);
    int n0 = ((jj >> 1) & 31) * 32;
    int b = bh >> 3, h = bh & 7;

    for (int t = tid; t < 2048; t += 512) {
        smask[t] = mbits[(size_t)n0 * 64 + t];
        sctx[t]  = 0.f;
    }
    __syncthreads();

    // Q A-fragments for both 16-row groups (Q pre-scaled by 1/8)
    h16x8 aQ[2][2];
#pragma unroll
    for (int g = 0; g < 2; ++g) {
        const u16* Qp = Qh + (((size_t)bh << 10) + n0 + g * 16 + m15) * 64 + q * 8;
        aQ[g][0] = *(const h16x8*)(Qp);
        aQ[g][1] = *(const h16x8*)(Qp + 32);
    }

    const u16* Kp = Kh + (((size_t)bh << 12) + (w << 9) + m15) * 64 + q * 8;
    const float L2E = 1.44269504f;

    // ---- Pass 1: l = sum exp(score) ----
    float ls[2][4] = {{0.f,0.f,0.f,0.f},{0.f,0.f,0.f,0.f}};
    for (int t4 = 0; t4 < 8; ++t4) {
        int widx = w * 8 + t4;
        u64 mk[2][4];
#pragma unroll
        for (int g = 0; g < 2; ++g)
#pragma unroll
            for (int r = 0; r < 4; ++r) mk[g][r] = smask[(g * 16 + q * 4 + r) * 64 + widx];
#pragma unroll
        for (int tt = 0; tt < 4; ++tt) {
            const u16* kp = Kp + (size_t)(t4 * 4 + tt) * (16 * 64);
            h16x8 b0 = *(const h16x8*)(kp);
            h16x8 b1 = *(const h16x8*)(kp + 32);
            f32x4 z = {0.f, 0.f, 0.f, 0.f};
            f32x4 c0 = mfma16(aQ[0][0], b0, mfma16(aQ[0][1], b1, z));
            f32x4 c1 = mfma16(aQ[1][0], b0, mfma16(aQ[1][1], b1, z));
            int bit = tt * 16 + m15;
#pragma unroll
            for (int r = 0; r < 4; ++r) {
                float p0 = ((mk[0][r] >> bit) & 1ull) ? exp2f(c0[r] * L2E) : 0.f;
                float p1 = ((mk[1][r] >> bit) & 1ull) ? exp2f(c1[r] * L2E) : 0.f;
                ls[0][r] += p0;
                ls[1][r] += p1;
            }
        }
    }
#pragma unroll
    for (int g = 0; g < 2; ++g)
#pragma unroll
        for (int r = 0; r < 4; ++r) {
            float v = redsum16(ls[g][r]);
            if (m15 == 0) sred[w][g * 16 + q * 4 + r] = v;
        }
    __syncthreads();
    if (tid < 32) {
        float ss = 0.f;
#pragma unroll
        for (int ww = 0; ww < 8; ++ww) ss += sred[ww][tid];
        srowi[tid] = 1.0f / ss;
    }
    __syncthreads();
    float iv[2][4];   // ctx-scale: row = q*4 + r
    float ivr[2][4];  // store-scale: row = s*4 + q
#pragma unroll
    for (int g = 0; g < 2; ++g)
#pragma unroll
        for (int r = 0; r < 4; ++r) {
            iv[g][r]  = srowi[g * 16 + q * 4 + r];
            ivr[g][r] = srowi[g * 16 + r * 4 + q];
        }

    // ---- Pass 2: recompute, per-group: P strip -> PV -> full-line stores ----
    const u16* Vp = Vt + (((size_t)bh << 6) + m15) * 4096 + (w << 9) + q * 8;
    int c0l = m15 * 4;   // 4-float column group for the store read-back

    f32x4 ctxa[2][4];
#pragma unroll
    for (int g = 0; g < 2; ++g)
#pragma unroll
        for (int dt = 0; dt < 4; ++dt) { f32x4 z = {0.f, 0.f, 0.f, 0.f}; ctxa[g][dt] = z; }

    for (int cc = 0; cc < 8; ++cc) {
        int widx = w * 8 + cc;
        u64 mk[2][4];
#pragma unroll
        for (int g = 0; g < 2; ++g)
#pragma unroll
            for (int r = 0; r < 4; ++r) mk[g][r] = smask[(g * 16 + q * 4 + r) * 64 + widx];

        float p1v[4][4];   // g=1 p-values parked in regs while strip holds g=0
#pragma unroll
        for (int tt = 0; tt < 4; ++tt) {
            const u16* kp = Kp + (size_t)(cc * 4 + tt) * (16 * 64);
            h16x8 b0 = *(const h16x8*)(kp);
            h16x8 b1 = *(const h16x8*)(kp + 32);
            f32x4 z = {0.f, 0.f, 0.f, 0.f};
            f32x4 c0 = mfma16(aQ[0][0], b0, mfma16(aQ[0][1], b1, z));
            f32x4 c1 = mfma16(aQ[1][0], b0, mfma16(aQ[1][1], b1, z));
            int bit = tt * 16 + m15;
#pragma unroll
            for (int r = 0; r < 4; ++r) {
                float p0 = ((mk[0][r] >> bit) & 1ull) ? exp2f(c0[r] * L2E) : 0.f;
                p1v[tt][r] = ((mk[1][r] >> bit) & 1ull) ? exp2f(c1[r] * L2E) : 0.f;
                sps[w][(q * 4 + r) * 72 + tt * 16 + m15] = f2h(p0);
            }
        }
        // V fragments cached once, reused by both groups
        h16x8 bV[2][4];
#pragma unroll
        for (int half = 0; half < 2; ++half)
#pragma unroll
            for (int dt = 0; dt < 4; ++dt)
                bV[half][dt] = *(const h16x8*)(Vp + (size_t)dt * (16 * 4096) + cc * 64 + half * 32);

#pragma unroll
        for (int g = 0; g < 2; ++g) {
            if (g == 1) {
                // swap strip to g=1 from parked regs
#pragma unroll
                for (int tt = 0; tt < 4; ++tt)
#pragma unroll
                    for (int r = 0; r < 4; ++r)
                        sps[w][(q * 4 + r) * 72 + tt * 16 + m15] = f2h(p1v[tt][r]);
            }
            // PV MFMA (unnormalized P; ctx scaled by 1/l at the end)
#pragma unroll
            for (int half = 0; half < 2; ++half) {
                h16x8 aP = *(const h16x8*)(&sps[w][m15 * 72 + half * 32 + q * 8]);
#pragma unroll
                for (int dt = 0; dt < 4; ++dt)
                    ctxa[g][dt] = mfma16(aP, bV[half][dt], ctxa[g][dt]);
            }
            // full-line attn stores: lane reads 4 contiguous fp16 of row s*4+q,
            // wave covers 4 rows x 256B contiguous per store instruction
            float* bp = attnO + (((size_t)bh << 10) + n0 + g * 16) * 4096 + (w << 9) + cc * 64 + c0l;
#pragma unroll
            for (int s = 0; s < 4; ++s) {
                int row = s * 4 + q;
                h16x4 hv = *(const h16x4*)(&sps[w][row * 72 + c0l]);
                f32x4 o;
                o[0] = (float)hv[0] * ivr[g][s];
                o[1] = (float)hv[1] * ivr[g][s];
                o[2] = (float)hv[2] * ivr[g][s];
                o[3] = (float)hv[3] * ivr[g][s];
                __builtin_nontemporal_store(o, (f32x4*)(bp + (size_t)row * 4096));
            }
        }
    }

    // ---- ctx reduce + store ----
#pragma unroll
    for (int g = 0; g < 2; ++g)
#pragma unroll
        for (int dt = 0; dt < 4; ++dt)
#pragma unroll
            for (int r = 0; r < 4; ++r)
                atomicAdd(&sctx[(g * 16 + q * 4 + r) * 64 + dt * 16 + m15],
                          ctxa[g][dt][r] * iv[g][r]);
    __syncthreads();
    for (int t = tid; t < 2048; t += 512) {
        int rr = t >> 6, d = t & 63;
        ctxO[(((size_t)b << 10) + n0 + rr) * 512 + h * 64 + d] = f2h(sctx[t]);
    }
}

// ---------- launch ----------
extern "C" void kernel_launch(void* const* d_in, const int* in_sizes, int n_in,
                              void* d_out, int out_size, void* d_ws, size_t ws_size,
                              hipStream_t stream) {
    (void)in_sizes; (void)n_in; (void)out_size; (void)ws_size;
    const float* query = (const float*)d_in[0];
    const float* key   = (const float*)d_in[1];
    const float* value = (const float*)d_in[2];
    const float* x_tilde = (const float*)d_in[3];
    const float* x_hat   = (const float*)d_in[4];
    const float* Wq = (const float*)d_in[5];  const float* bq = (const float*)d_in[6];
    const float* Wk = (const float*)d_in[7];  const float* bk = (const float*)d_in[8];
    const float* Wv = (const float*)d_in[9];  const float* bv = (const float*)d_in[10];
    const float* Wo = (const float*)d_in[11]; const float* bo = (const float*)d_in[12];

    char* ws = (char*)d_ws;
    u16* wq   = (u16*)(ws + 0);
    u16* wk   = (u16*)(ws + 524288);
    u16* wv   = (u16*)(ws + 1048576);
    u16* wo   = (u16*)(ws + 1572864);
    u16* Qh   = (u16*)(ws + 2097152);    // (bh, 1024, 64) fp16, pre-scaled 1/8
    u16* Kh   = (u16*)(ws + 6291456);    // (bh, 4096, 64) fp16
    u16* Vtb  = (u16*)(ws + 23068672);   // (bh, 64, 4096) fp16
    u16* ctxb = (u16*)(ws + 39845888);   // (B*N, 512) fp16
    u64* mbits = (u64*)(ws + 44040192);  // (1024, 64) u64

    cvt_h_kernel<<<256, 256, 0, stream>>>(Wq, wq, 0.125f);  // fold 1/sqrt(dk) into Q
    cvt_h_kernel<<<256, 256, 0, stream>>>(Wk, wk, 1.0f);
    cvt_h_kernel<<<256, 256, 0, stream>>>(Wv, wv, 1.0f);
    cvt_h_kernel<<<256, 256, 0, stream>>>(Wo, wo, 1.0f);
    mask_kernel<<<16384, 256, 0, stream>>>(x_tilde, x_hat, mbits);

    proj_kernel<1, 3, 10><<<dim3(32, 4),  256, 0, stream>>>(query, wq, bq, 0.125f, Qh);
    proj_kernel<1, 3, 12><<<dim3(128, 4), 256, 0, stream>>>(key,   wk, bk, 1.0f,   Kh);
    proj_kernel<1, 1, 12><<<dim3(128, 4), 256, 0, stream>>>(value, wv, bv, 1.0f,   Vtb);

    float* attnO = (float*)d_out + 2097152;
    attn_kernel<<<1024, 512, 0, stream>>>(Qh, Kh, Vtb, mbits, attnO, ctxb);

    proj_kernel<0, 2, 10><<<dim3(32, 4), 256, 0, stream>>>(ctxb, wo, bo, 1.0f, d_out);
}